// Round 1
// baseline (227.973 us; speedup 1.0000x reference)
//
#include <hip/hip_runtime.h>

// Problem constants (from reference):
//   VOCAB=50000, DIM=300, PAD=0, UNK=1, CTX_W=2, B=32, S=4096
// Inputs: d_in[0] = input_ids (B*S int32), d_in[1] = table (VOCAB*DIM f32)
// Output: d_out = (B, S, DIM) f32
//
// Pure memory-bound gather. One thread per float4 of output (75 per token).
// UNK tokens (~5%) take the context-average branch: masked mean of the up to
// 4 valid neighbors (center is UNK -> masked out in reference too).

#define PAD_ID 0
#define UNK_ID 1
#define SEQ    4096          // power of two -> cheap row masking
#define DIM4   75            // 300 / 4

__global__ __launch_bounds__(256) void w2v_embed_kernel(
    const int* __restrict__ ids,
    const float4* __restrict__ table4,   // row stride DIM4 float4 (1200 B, 16B-aligned)
    float4* __restrict__ out4,
    int total4)
{
    int i = blockIdx.x * blockDim.x + threadIdx.x;
    if (i >= total4) return;

    int t = i / DIM4;            // token index in [0, B*S)
    int d = i - t * DIM4;        // float4 index within the 300-dim row

    int id = ids[t];
    if (id != UNK_ID) {
        // emb = table[id]; PAD row is zero in the table, so plain copy.
        out4[i] = table4[id * DIM4 + d];
        return;
    }

    // UNK: average of valid neighbors within +-2 in the same sequence row.
    int s = t & (SEQ - 1);
    float sx = 0.f, sy = 0.f, sz = 0.f, sw = 0.f;
    float cnt = 0.f;
#pragma unroll
    for (int k = -2; k <= 2; ++k) {
        if (k == 0) continue;
        int sn = s + k;
        if (sn < 0 || sn >= SEQ) continue;       // zero-pad beyond row edges
        int idn = ids[t + k];
        if (idn == PAD_ID || idn == UNK_ID) continue;  // masked out
        float4 v = table4[idn * DIM4 + d];
        sx += v.x; sy += v.y; sz += v.z; sw += v.w;
        cnt += 1.f;
    }
    float denom = cnt + 1e-8f;                   // cnt==0 -> sum==0 -> out 0
    float4 r;
    r.x = sx / denom; r.y = sy / denom; r.z = sz / denom; r.w = sw / denom;
    out4[i] = r;
}

extern "C" void kernel_launch(void* const* d_in, const int* in_sizes, int n_in,
                              void* d_out, int out_size, void* d_ws, size_t ws_size,
                              hipStream_t stream)
{
    const int*    ids    = (const int*)d_in[0];
    const float4* table4 = (const float4*)d_in[1];
    float4*       out4   = (float4*)d_out;

    int total4 = out_size / 4;   // 32*4096*300/4 = 9,830,400
    int block = 256;
    int grid = (total4 + block - 1) / block;
    w2v_embed_kernel<<<grid, block, 0, stream>>>(ids, table4, out4, total4);
}

// Round 3
// 221.259 us; speedup vs baseline: 1.0303x; 1.0303x over previous
//
#include <hip/hip_runtime.h>

// Word2VecEmbedding: gather table[ids] with ~5% UNK tokens replaced by the
// masked mean of the +-2 context window.
//   VOCAB=50000, DIM=300, PAD=0, UNK=1, CTX_W=2, B=32, S=4096
// d_in[0] = input_ids (B*S int32), d_in[1] = table (VOCAB*DIM f32)
// d_out   = (B,S,DIM) f32
//
// R2: same as R1 but with clang ext_vector float4 so
// __builtin_nontemporal_store compiles (HIP_vector_type is rejected).

#define PAD_ID 0
#define UNK_ID 1
#define SEQ    4096
#define DIM4   75
#define ITEMS  4

typedef float vf4 __attribute__((ext_vector_type(4)));

__global__ __launch_bounds__(256) void w2v_embed_kernel(
    const int* __restrict__ ids,
    const vf4* __restrict__ table4,
    vf4* __restrict__ out4,
    int total4)
{
    const int tid  = threadIdx.x;
    const int base = blockIdx.x * (256 * ITEMS) + tid;

    int   ii[ITEMS], tt[ITEMS], dd[ITEMS], idv[ITEMS];
    bool  ok[ITEMS];

    // Phase 1: indices + batched ids loads (4 independent loads in flight)
#pragma unroll
    for (int u = 0; u < ITEMS; ++u) {
        int i = base + u * 256;
        ii[u] = i;
        ok[u] = (i < total4);
        int t = i / DIM4;                 // magic-mul
        tt[u] = t;
        dd[u] = i - t * DIM4;
        idv[u] = ok[u] ? ids[t] : 0;
    }

    // Phase 2: batched center-row gathers (unconditional; row UNK_ID=1 is a
    // real table row, loading it for UNK lanes is harmless and keeps the 4
    // loads independent + back-to-back).
    vf4 val[ITEMS];
#pragma unroll
    for (int u = 0; u < ITEMS; ++u) {
        val[u] = ok[u] ? table4[idv[u] * DIM4 + dd[u]] : (vf4)0.f;
    }

    // Phase 3: rare UNK repair (~5% of lanes)
#pragma unroll
    for (int u = 0; u < ITEMS; ++u) {
        if (ok[u] && idv[u] == UNK_ID) {
            int t = tt[u], d = dd[u];
            int s = t & (SEQ - 1);
            vf4 acc = (vf4)0.f;
            float cnt = 0.f;
#pragma unroll
            for (int k = -2; k <= 2; ++k) {
                if (k == 0) continue;
                int sn = s + k;
                if (sn < 0 || sn >= SEQ) continue;      // zero-pad at edges
                int idn = ids[t + k];
                if (idn == PAD_ID || idn == UNK_ID) continue;
                acc += table4[idn * DIM4 + d];
                cnt += 1.f;
            }
            float inv = 1.f / (cnt + 1e-8f);            // cnt==0 -> zeros
            val[u] = acc * inv;
        }
    }

    // Phase 4: nontemporal streaming stores (protect table residency in L2/L3)
#pragma unroll
    for (int u = 0; u < ITEMS; ++u) {
        if (ok[u]) __builtin_nontemporal_store(val[u], &out4[ii[u]]);
    }
}

extern "C" void kernel_launch(void* const* d_in, const int* in_sizes, int n_in,
                              void* d_out, int out_size, void* d_ws, size_t ws_size,
                              hipStream_t stream)
{
    const int* ids    = (const int*)d_in[0];
    const vf4* table4 = (const vf4*)d_in[1];
    vf4*       out4   = (vf4*)d_out;

    int total4 = out_size / 4;                         // 9,830,400
    int per_block = 256 * ITEMS;
    int grid = (total4 + per_block - 1) / per_block;   // 9600
    w2v_embed_kernel<<<grid, 256, 0, stream>>>(ids, table4, out4, total4);
}